// Round 1
// 77.282 us; speedup vs baseline: 1.0675x; 1.0675x over previous
//
#include <hip/hip_runtime.h>

// YOLO layer: x (32, 255, 76, 76) fp32 -> out (32, 76*76*3, 85) fp32
// out flat = b*(76*76*255) + h*(76*255) + w*255 + (a*85 + attr)
//          = f(x[b][a*85+attr][h][w])
//   attr 0: (sigmoid(v) + w) * 8     attr 2: exp(v) * {10,16,33}[a]
//   attr 1: (sigmoid(v) + h) * 8     attr 3: exp(v) * {13,30,23}[a]
//   else  : sigmoid(v)
//
// Block = (b, h). LDS tile[w][ch], stride exactly 255 -> tile flat layout ==
// output flat layout for the block.
// SINGLE-PASS version: the special-channel pattern repeats every 255 f4s
// (= 4 w-rows), so 255 threads build a per-(i%255) descriptor word in LDS
// (1 byte per f4 lane: special|attr|anchor|w-offset). The bulk loop applies
// the box math inline on flagged lanes and stores each output dword EXACTLY
// ONCE -> no second barrier, no vmcnt(0) store drain, no RMW re-dirtying of
// ~38 MB of nt-evicted lines.
// Also: XCD-contiguous block remap (2432 % 8 == 0 -> bijective) so adjacent-h
// blocks (which share misaligned 304 B input row-segment lines) land on the
// same XCD L2.

typedef float f4 __attribute__((ext_vector_type(4)));

constexpr int NB = 32;
constexpr int NH = 76;
constexpr int NW = 76;
constexpr int C = 255;                 // 3 anchors * 85
constexpr int ROW_F4 = NW / 4;         // 19 f4 per input row
constexpr int BLK_F4 = C * ROW_F4;     // 4845 f4 = 19380 floats per block
constexpr float STRIDE = 8.0f;

__device__ __forceinline__ float sigmoidf_(float v) {
    return 1.0f / (1.0f + __expf(-v));
}

__global__ __launch_bounds__(1024) void yolo_kernel(const f4* __restrict__ x4,
                                                    f4* __restrict__ out4) {
    __shared__ f4 tile4[BLK_F4];               // 77520 B
    __shared__ unsigned int desc[C];           // +1020 B -> still 2 blocks/CU
    float* __restrict__ tile = (float*)tile4;

    // ---- XCD-contiguous remap: physical bid -> logical blk ----
    const int bid = blockIdx.x;
    const int blk = (bid & 7) * (NB * NH / 8) + (bid >> 3);
    const int h = blk % NH;
    const int b = blk / NH;

    // ---- phase 0: per-(i%255) f4 descriptor (block-invariant pattern) ----
    // byte j of desc[m] describes lane j of any f4 with i%255==m:
    //   bit0   = special (attr < 4)
    //   bit1-2 = attr (0..3)
    //   bit3-4 = anchor (0..2)
    //   bit5-6 = w offset within the 4-w group (0..3)
    if (threadIdx.x < C) {
        const int m = threadIdx.x;
        unsigned int d = 0;
#pragma unroll
        for (int j = 0; j < 4; ++j) {
            const int g = 4 * m + j;           // float idx within 4-w group
            const int wl = g / 255;            // 0..3
            const int ch = g - 255 * wl;       // 0..254
            const int a = ch / 85;             // anchor 0..2
            const int amod = ch - 85 * a;      // attr within anchor
            if (amod < 4)
                d |= (1u | ((unsigned)amod << 1) | ((unsigned)a << 3) |
                      ((unsigned)wl << 5)) << (8 * j);
        }
        desc[m] = d;
    }

    // ---- phase 1: 255 rows x 19 f4 coalesced, scatter-transpose into LDS ----
    const size_t in_base = (size_t)b * (C * NH * ROW_F4) + (size_t)h * ROW_F4;
    for (int i = threadIdx.x; i < BLK_F4; i += 1024) {
        const int row = i / ROW_F4;            // channel 0..254
        const int c   = i - row * ROW_F4;      // f4 index along w
        const f4 v = x4[in_base + (size_t)row * (NH * ROW_F4) + c];
        const int base = (4 * c) * C + row;    // tile[w=4c+k][ch=row]
        tile[base]         = v.x;
        tile[base + C]     = v.y;
        tile[base + 2 * C] = v.z;
        tile[base + 3 * C] = v.w;
    }
    __syncthreads();

    // ---- phase 2 (fused): sigmoid bulk + inline box fixup, single store ----
    const size_t out_base = (size_t)blk * BLK_F4;
    for (int i = threadIdx.x; i < BLK_F4; i += 1024) {
        const f4 v = tile4[i];
        f4 r;
        r.x = sigmoidf_(v.x);
        r.y = sigmoidf_(v.y);
        r.z = sigmoidf_(v.z);
        r.w = sigmoidf_(v.w);

        const int q = i / C;                   // w-group (w = 4q + wl)
        const int m = i - q * C;
        const unsigned int d = desc[m];
        if (d) {
#pragma unroll
            for (int j = 0; j < 4; ++j) {
                const unsigned int bj = (d >> (8 * j)) & 0xffu;
                if (bj & 1u) {
                    const int attr = (bj >> 1) & 3;
                    const int anc  = (bj >> 3) & 3;
                    const int wl   = (bj >> 5) & 3;
                    float o;
                    if (attr < 2) {
                        const float off =
                            (attr == 0) ? (float)(4 * q + wl) : (float)h;
                        o = (r[j] + off) * STRIDE;   // r[j] already sigmoid(v)
                    } else {
                        const float aw = (anc == 0) ? 10.0f
                                       : ((anc == 1) ? 16.0f : 33.0f);
                        const float ah = (anc == 0) ? 13.0f
                                       : ((anc == 1) ? 30.0f : 23.0f);
                        o = __expf(v[j]) * ((attr == 2) ? aw : ah);
                    }
                    r[j] = o;
                }
            }
        }
        __builtin_nontemporal_store(r, &out4[out_base + i]);
    }
}

extern "C" void kernel_launch(void* const* d_in, const int* in_sizes, int n_in,
                              void* d_out, int out_size, void* d_ws, size_t ws_size,
                              hipStream_t stream) {
    const f4* x4 = (const f4*)d_in[0];
    f4* out4 = (f4*)d_out;
    const int grid = NB * NH;                  // 2432 blocks, 2432 % 8 == 0
    yolo_kernel<<<grid, 1024, 0, stream>>>(x4, out4);
}

// Round 2
// 73.293 us; speedup vs baseline: 1.1256x; 1.0544x over previous
//
#include <hip/hip_runtime.h>

// YOLO layer: x (32, 255, 76, 76) fp32 -> out (32, 76*76*3, 85) fp32
// out flat = b*(76*76*255) + h*(76*255) + w*255 + (a*85 + attr)
//          = f(x[b][a*85+attr][h][w])
//   attr 0: (sigmoid(v) + w) * 8     attr 2: exp(v) * {10,16,33}[a]
//   attr 1: (sigmoid(v) + h) * 8     attr 3: exp(v) * {13,30,23}[a]
//   else  : sigmoid(v)
//
// PERSISTENT DOUBLE-BUFFERED PIPELINE (1 block/CU, 256 blocks, ~9.5 tiles each):
// per tile t:
//   A: issue global loads for tile t+256 into registers   (latency hidden by B)
//   B: stream buf[cur] -> out   (pure ds_read_b128 + nt store, NO math)
//   C: transform staged regs (full YOLO math, thread-invariant mode precomputed)
//      + scatter-transpose into buf[cur^1]                (in load-latency shadow)
//   D: one __syncthreads per tile
// The transform result is written to LDS, so the store phase B carries zero
// per-element math (round-1's desc-read + i/C + divergent fixup are gone from
// the critical store path). Two LDS buffers (155 KB) make B-reads and C-writes
// hazard-free without an extra barrier.

typedef float f4 __attribute__((ext_vector_type(4)));

constexpr int NB = 32;
constexpr int NH = 76;
constexpr int NW = 76;
constexpr int C = 255;                 // 3 anchors * 85
constexpr int ROW_F4 = NW / 4;         // 19 f4 per input row
constexpr int BLK_F4 = C * ROW_F4;     // 4845 f4 per tile
constexpr int TILES = NB * NH;         // 2432
constexpr int NTH = 1024;
constexpr int KMAX = 5;                // ceil(4845/1024)
constexpr int GRID = 256;              // 1 block per CU
constexpr float STRIDE = 8.0f;

__device__ __forceinline__ float sigmoidf_(float v) {
    return 1.0f / (1.0f + __expf(-v));
}

__global__ __launch_bounds__(NTH) void yolo_kernel(const f4* __restrict__ x4,
                                                   f4* __restrict__ out4) {
    __shared__ f4 buf[2][BLK_F4];      // 155040 B -> 1 block/CU

    const int tid = threadIdx.x;

    // ---- thread-invariant per-k geometry & transform descriptors ----
    int offk[KMAX];      // input f4 offset within tile: row*(NH*ROW_F4)+c
    int basek[KMAX];     // LDS scatter base (floats): 4*c*C + row
    int modek[KMAX];     // 0 plain sigmoid, 1 bx, 2 by, 3 exp*scale
    float scalek[KMAX];  // anchor scale for mode 3
    float w0k[KMAX];     // w base for mode 1
    bool act[KMAX];

#pragma unroll
    for (int k = 0; k < KMAX; ++k) {
        const int i = tid + k * NTH;
        act[k] = (i < BLK_F4);
        const int ii = act[k] ? i : 0;
        const int row = ii / ROW_F4;           // channel 0..254
        const int c = ii - row * ROW_F4;       // f4 index along w
        offk[k] = row * (NH * ROW_F4) + c;
        basek[k] = 4 * c * C + row;
        const int a = (row >= 170) ? 2 : ((row >= 85) ? 1 : 0);
        const int attr = row - 85 * a;
        int mode = 0;
        float sc = 0.0f;
        if (attr == 0) mode = 1;
        else if (attr == 1) mode = 2;
        else if (attr == 2) { mode = 3; sc = (a == 0) ? 10.f : ((a == 1) ? 16.f : 33.f); }
        else if (attr == 3) { mode = 3; sc = (a == 0) ? 13.f : ((a == 1) ? 30.f : 23.f); }
        modek[k] = mode;
        scalek[k] = sc;
        w0k[k] = (float)(4 * c);
    }

    f4 stage[KMAX];

    auto load_tile = [&](int t) {
        const int b = t / NH;
        const int h = t - b * NH;
        const size_t inb = (size_t)b * (C * NH * ROW_F4) + (size_t)h * ROW_F4;
#pragma unroll
        for (int k = 0; k < KMAX; ++k)
            if (act[k]) stage[k] = x4[inb + offk[k]];
    };

    auto transform_store = [&](int t, int nxt) {
        const float hf = (float)(t % NH);
        float* __restrict__ tb = (float*)buf[nxt];
#pragma unroll
        for (int k = 0; k < KMAX; ++k) {
            if (!act[k]) continue;
            const f4 v = stage[k];
            f4 r;
            if (modek[k] == 3) {
                r.x = __expf(v.x) * scalek[k];
                r.y = __expf(v.y) * scalek[k];
                r.z = __expf(v.z) * scalek[k];
                r.w = __expf(v.w) * scalek[k];
            } else {
                r.x = sigmoidf_(v.x);
                r.y = sigmoidf_(v.y);
                r.z = sigmoidf_(v.z);
                r.w = sigmoidf_(v.w);
                if (modek[k] == 1) {
                    r.x = (r.x + w0k[k]) * STRIDE;
                    r.y = (r.y + w0k[k] + 1.0f) * STRIDE;
                    r.z = (r.z + w0k[k] + 2.0f) * STRIDE;
                    r.w = (r.w + w0k[k] + 3.0f) * STRIDE;
                } else if (modek[k] == 2) {
                    r.x = (r.x + hf) * STRIDE;
                    r.y = (r.y + hf) * STRIDE;
                    r.z = (r.z + hf) * STRIDE;
                    r.w = (r.w + hf) * STRIDE;
                }
            }
            const int base = basek[k];
            tb[base]         = r.x;
            tb[base + C]     = r.y;
            tb[base + 2 * C] = r.z;
            tb[base + 3 * C] = r.w;
        }
    };

    // ---- prologue: fill buf[0] with tile bid ----
    int t = blockIdx.x;
    load_tile(t);
    transform_store(t, 0);
    __syncthreads();
    int cur = 0;

    // ---- steady state ----
    while (true) {
        const int tn = t + GRID;
        const bool have_next = (tn < TILES);

        if (have_next) load_tile(tn);          // A: issue next loads

        const size_t ob = (size_t)t * BLK_F4;  // B: pure streaming copy
#pragma unroll
        for (int k = 0; k < KMAX; ++k) {
            const int i = tid + k * NTH;
            if (i < BLK_F4)
                __builtin_nontemporal_store(buf[cur][i], &out4[ob + i]);
        }

        if (!have_next) break;
        transform_store(tn, cur ^ 1);          // C: math in latency shadow
        __syncthreads();                       // D: publish buf[cur^1]
        cur ^= 1;
        t = tn;
    }
}

extern "C" void kernel_launch(void* const* d_in, const int* in_sizes, int n_in,
                              void* d_out, int out_size, void* d_ws, size_t ws_size,
                              hipStream_t stream) {
    const f4* x4 = (const f4*)d_in[0];
    f4* out4 = (f4*)d_out;
    yolo_kernel<<<GRID, NTH, 0, stream>>>(x4, out4);
}

// Round 3
// 70.609 us; speedup vs baseline: 1.1684x; 1.0380x over previous
//
#include <hip/hip_runtime.h>

// YOLO layer: x (32, 255, 76, 76) fp32 -> out (32, 76*76*3, 85) fp32
// out flat = b*(76*76*255) + h*(76*255) + w*255 + (a*85 + attr)
//          = f(x[b][a*85+attr][h][w])
//   attr 0: (sigmoid(v) + w) * 8     attr 2: exp(v) * {10,16,33}[a]
//   attr 1: (sigmoid(v) + h) * 8     attr 3: exp(v) * {13,30,23}[a]
//   else  : sigmoid(v)
//
// PERSISTENT SINGLE-BUFFER PIPELINE, 2 blocks/CU (512 blocks, 4-5 tiles each):
//   - LDS = one 77.5 KB tile buffer -> 2 blocks resident -> up to 32 waves/CU
//     (round-2's 155 KB double buffer capped occupancy at 41%; barriers had
//     nothing to overlap with). __launch_bounds__(1024,8) pins VGPR<=64, the
//     residency condition for 2x16-wave blocks.
//   - per tile: transform staged regs IN PLACE (per-thread mode precomputed,
//     zero math on the store path) -> barrier -> scatter to LDS -> issue next
//     tile's loads -> barrier -> contiguous ds_read_b128 + nt store.
//   - XCD-contiguous tile map: XCD x owns tiles [304x, 304x+304); its 64
//     blocks take ADJACENT tiles each epoch, so the misaligned 304 B input
//     row-segments' shared boundary lines hit the same XCD L2 (round 2 spread
//     neighbors across XCDs: FETCH 92->126 MB regression).

typedef float f4 __attribute__((ext_vector_type(4)));

constexpr int NB = 32;
constexpr int NH = 76;
constexpr int NW = 76;
constexpr int C = 255;                 // 3 anchors * 85
constexpr int ROW_F4 = NW / 4;         // 19 f4 per input row
constexpr int BLK_F4 = C * ROW_F4;     // 4845 f4 per tile
constexpr int TILES = NB * NH;         // 2432
constexpr int NTH = 1024;
constexpr int KMAX = 5;                // ceil(4845/1024)
constexpr int TAIL = BLK_F4 - 4 * NTH; // 749 (k==4 active threads)
constexpr int GRID = 512;              // 2 blocks per CU
constexpr int NXCD = 8;
constexpr int PER_XCD = TILES / NXCD;        // 304
constexpr int BLKS_PER_XCD = GRID / NXCD;    // 64
constexpr float STRIDE = 8.0f;

__device__ __forceinline__ float sigmoidf_(float v) {
    return 1.0f / (1.0f + __expf(-v));
}

__global__ __launch_bounds__(NTH, 8) void yolo_kernel(const f4* __restrict__ x4,
                                                      f4* __restrict__ out4) {
    __shared__ f4 buf[BLK_F4];         // 77520 B -> 2 blocks/CU

    const int tid = threadIdx.x;

    // ---- thread-invariant per-k geometry & transform descriptors ----
    int offk[KMAX];      // input f4 offset within tile: row*(NH*ROW_F4)+c
    int basek[KMAX];     // LDS scatter base (floats): 4*c*C + row
    int modek[KMAX];     // 0 plain sigmoid, 1 bx, 2 by, 3 exp*scale
    float auxk[KMAX];    // mode 1: w base; mode 3: anchor scale

#pragma unroll
    for (int k = 0; k < KMAX; ++k) {
        const int i = tid + k * NTH;
        const int ii = (k < 4 || tid < TAIL) ? i : 0;
        const int row = ii / ROW_F4;           // channel 0..254
        const int c = ii - row * ROW_F4;       // f4 index along w
        offk[k] = row * (NH * ROW_F4) + c;
        basek[k] = 4 * c * C + row;
        const int a = (row >= 170) ? 2 : ((row >= 85) ? 1 : 0);
        const int attr = row - 85 * a;
        int mode = 0;
        float aux = (float)(4 * c);            // default: w base (mode 1)
        if (attr == 0) mode = 1;
        else if (attr == 1) mode = 2;
        else if (attr == 2) { mode = 3; aux = (a == 0) ? 10.f : ((a == 1) ? 16.f : 33.f); }
        else if (attr == 3) { mode = 3; aux = (a == 0) ? 13.f : ((a == 1) ? 30.f : 23.f); }
        modek[k] = mode;
        auxk[k] = aux;
    }

    // ---- XCD-contiguous tile assignment ----
    const int x = blockIdx.x & (NXCD - 1);     // XCD (dispatch round-robin)
    const int j = blockIdx.x >> 3;             // block index within XCD, 0..63
    const int base_t = x * PER_XCD;
    const int ntile = 4 + (j < (PER_XCD - 4 * BLKS_PER_XCD) ? 1 : 0);  // 4 or 5

    f4 stage[KMAX];

    auto issue = [&](int t) {
        const int b = t / NH;
        const int h = t - b * NH;
        const size_t inb = (size_t)b * (C * NH * ROW_F4) + (size_t)h * ROW_F4;
#pragma unroll
        for (int k = 0; k < KMAX; ++k)
            if (k < 4 || tid < TAIL) stage[k] = x4[inb + offk[k]];
    };

    int t = base_t + j;                        // tile for idx 0
    issue(t);
    int idx = 0;
    float* __restrict__ tb = (float*)buf;

    while (true) {
        // ---- transform stage in place (waits on global loads) ----
        const float hf = (float)(t % NH);
#pragma unroll
        for (int k = 0; k < KMAX; ++k) {
            if (!(k < 4 || tid < TAIL)) continue;
            const f4 v = stage[k];
            f4 r;
            if (modek[k] == 3) {
                r.x = __expf(v.x) * auxk[k];
                r.y = __expf(v.y) * auxk[k];
                r.z = __expf(v.z) * auxk[k];
                r.w = __expf(v.w) * auxk[k];
            } else {
                r.x = sigmoidf_(v.x);
                r.y = sigmoidf_(v.y);
                r.z = sigmoidf_(v.z);
                r.w = sigmoidf_(v.w);
                if (modek[k] == 1) {
                    r.x = (r.x + auxk[k]) * STRIDE;
                    r.y = (r.y + auxk[k] + 1.0f) * STRIDE;
                    r.z = (r.z + auxk[k] + 2.0f) * STRIDE;
                    r.w = (r.w + auxk[k] + 3.0f) * STRIDE;
                } else if (modek[k] == 2) {
                    r.x = (r.x + hf) * STRIDE;
                    r.y = (r.y + hf) * STRIDE;
                    r.z = (r.z + hf) * STRIDE;
                    r.w = (r.w + hf) * STRIDE;
                }
            }
            stage[k] = r;
        }

        if (idx > 0) __syncthreads();          // prev store-phase reads done

        // ---- scatter-transpose transformed values into LDS ----
#pragma unroll
        for (int k = 0; k < KMAX; ++k) {
            if (!(k < 4 || tid < TAIL)) continue;
            const f4 r = stage[k];
            const int base = basek[k];
            tb[base]         = r.x;
            tb[base + C]     = r.y;
            tb[base + 2 * C] = r.z;
            tb[base + 3 * C] = r.w;
        }

        const size_t ob = (size_t)t * BLK_F4;
        ++idx;
        const bool more = (idx < ntile);
        if (more) {                            // issue next tile's loads now:
            t = base_t + idx * BLKS_PER_XCD + j;
            issue(t);                          // latency hides under store phase
        }

        __syncthreads();                       // LDS writes visible

        // ---- pure streaming store: contiguous b128 reads + nt stores ----
#pragma unroll
        for (int k = 0; k < KMAX; ++k) {
            const int i = tid + k * NTH;
            if (k < 4 || tid < TAIL)
                __builtin_nontemporal_store(buf[i], &out4[ob + i]);
        }

        if (!more) break;
    }
}

extern "C" void kernel_launch(void* const* d_in, const int* in_sizes, int n_in,
                              void* d_out, int out_size, void* d_ws, size_t ws_size,
                              hipStream_t stream) {
    const f4* x4 = (const f4*)d_in[0];
    f4* out4 = (f4*)d_out;
    yolo_kernel<<<GRID, NTH, 0, stream>>>(x4, out4);
}